// Round 2
// baseline (15066.602 us; speedup 1.0000x reference)
//
#include <hip/hip_runtime.h>
#include <hip/hip_bf16.h>
#include <stdint.h>

typedef unsigned short u16;
typedef unsigned int   u32;
typedef unsigned long long u64;

typedef __attribute__((ext_vector_type(4))) float  f32x4;
typedef __attribute__((ext_vector_type(8))) short  bf16x8;
typedef __attribute__((ext_vector_type(8))) unsigned short us8;

#define T_LEN 2048
#define BATCH 32
#define IDIM  512
#define HDIM  512
#define G4    2048

// workspace layout (bytes)
#define XBF_OFF   0ull            // bf16 x            : 33554432 u16 (67108864 B)
#define WIH_OFF   67108864ull     // bf16 wih[2][2048][512]
#define WHH_OFF   71303168ull     // bf16 whh[2][2048][512]
#define XP_OFF    75497472ull     // bf16 xp[2][T][64][1024] (scan-friendly permuted layout)
#define HBUF_OFF  612368384ull    // bf16 hbuf[2][2 slots][32][512]
#define FLG_OFF   612499456ull    // u32 counters[2][2] (+pad)
#define WS_NEED   612499968ull

__device__ __forceinline__ u16 f2bf(float f) {
  u32 u = __float_as_uint(f);
  return (u16)((u + 0x7FFFu + ((u >> 16) & 1u)) >> 16);   // RTNE
}
__device__ __forceinline__ float bf2f(u16 h) {
  return __uint_as_float(((u32)h) << 16);
}
__device__ __forceinline__ float sigm(float x) {
  x = fminf(fmaxf(x, -30.f), 30.f);
  return 1.f / (1.f + __expf(-x));
}
__device__ __forceinline__ float tanh_(float x) {
  x = fminf(fmaxf(x, -15.f), 15.f);
  float e = __expf(2.f * x);
  return (e - 1.f) / (e + 1.f);
}

// ---------------- prep: fp32 -> bf16 conversions + h0 seed + counter reset ----------------
__global__ __launch_bounds__(256) void prep_kernel(
    const float4* __restrict__ x,
    const float4* __restrict__ wihf, const float4* __restrict__ wihb,
    const float4* __restrict__ whhf, const float4* __restrict__ whhb,
    const float4* __restrict__ h0f,  const float4* __restrict__ h0b,
    ushort4* __restrict__ xbf, ushort4* __restrict__ wihbf,
    ushort4* __restrict__ whhbf, ushort4* __restrict__ hbuf,
    u32* __restrict__ flags)
{
  if (blockIdx.x == 0 && threadIdx.x < 128) flags[threadIdx.x] = 0;
  const size_t NX = 8388608, NW = 262144, NH = 4096;   // float4 units
  const size_t total = NX + 4 * NW + 2 * NH;
  size_t stride = (size_t)gridDim.x * blockDim.x;
  for (size_t i = (size_t)blockIdx.x * blockDim.x + threadIdx.x; i < total; i += stride) {
    const float4* src; ushort4* dst; size_t off;
    if (i < NX)                { src = x;    dst = xbf;          off = i; }
    else if (i < NX + NW)      { src = wihf; dst = wihbf;        off = i - NX; }
    else if (i < NX + 2 * NW)  { src = wihb; dst = wihbf + NW;   off = i - NX - NW; }
    else if (i < NX + 3 * NW)  { src = whhf; dst = whhbf;        off = i - NX - 2 * NW; }
    else if (i < NX + 4 * NW)  { src = whhb; dst = whhbf + NW;   off = i - NX - 3 * NW; }
    else if (i < NX + 4 * NW + NH) { src = h0f; dst = hbuf;        off = i - NX - 4 * NW; }
    else                       { src = h0b; dst = hbuf + 8192;   off = i - NX - 4 * NW - NH; }
    float4 v = src[off];
    ushort4 o;
    o.x = f2bf(v.x); o.y = f2bf(v.y); o.z = f2bf(v.z); o.w = f2bf(v.w);
    dst[off] = o;
  }
}

// ---------------- x-projection GEMM: xp = x @ Wih^T + b (both dirs), permuted store --------
// M=65536 (t*32+b), N=2048 (g*512 + w*8 + jj), K=512. 128x128 tile, 4 waves, bf16 MFMA.
__global__ __launch_bounds__(256, 2) void gemm_xp(
    const u16* __restrict__ xbf, const u16* __restrict__ wihbf,
    const float* __restrict__ bias_f, const float* __restrict__ bias_b,
    u16* __restrict__ xpo)
{
  const int m0 = blockIdx.x * 128;
  const int n0 = blockIdx.y * 128;
  const int dir = blockIdx.z;
  const int tid = threadIdx.x, l = tid & 63, wv = tid >> 6;

  __shared__ u16 As[128 * 72];   // padded rows (+8 bf16) to break bank conflicts
  __shared__ u16 Bs[128 * 72];

  const u16* wih = wihbf + (size_t)dir * G4 * IDIM;

  f32x4 acc[4][4];
#pragma unroll
  for (int i = 0; i < 4; i++)
#pragma unroll
    for (int j = 0; j < 4; j++) acc[i][j] = (f32x4){0.f, 0.f, 0.f, 0.f};

  const int srow = tid >> 1, shalf = tid & 1;
  const int wr = wv >> 1, wc = wv & 1;

  for (int k0 = 0; k0 < IDIM; k0 += 64) {
    __syncthreads();
    {
      const u16* ag = xbf + (size_t)(m0 + srow) * IDIM + k0 + shalf * 32;
      const u16* bg = wih + (size_t)(n0 + srow) * IDIM + k0 + shalf * 32;
      u16* ad = &As[srow * 72 + shalf * 32];
      u16* bd = &Bs[srow * 72 + shalf * 32];
#pragma unroll
      for (int q = 0; q < 4; q++) *(us8*)(ad + q * 8) = *(const us8*)(ag + q * 8);
#pragma unroll
      for (int q = 0; q < 4; q++) *(us8*)(bd + q * 8) = *(const us8*)(bg + q * 8);
    }
    __syncthreads();
#pragma unroll
    for (int kk = 0; kk < 2; kk++) {
      bf16x8 af[4], bv[4];
#pragma unroll
      for (int i = 0; i < 4; i++)
        af[i] = *(const bf16x8*)&As[(wr * 64 + i * 16 + (l & 15)) * 72 + kk * 32 + (l >> 4) * 8];
#pragma unroll
      for (int j = 0; j < 4; j++)
        bv[j] = *(const bf16x8*)&Bs[(wc * 64 + j * 16 + (l & 15)) * 72 + kk * 32 + (l >> 4) * 8];
#pragma unroll
      for (int i = 0; i < 4; i++)
#pragma unroll
        for (int j = 0; j < 4; j++)
          acc[i][j] = __builtin_amdgcn_mfma_f32_16x16x32_bf16(af[i], bv[j], acc[i][j], 0, 0, 0);
    }
  }

  const float* bias = dir ? bias_b : bias_f;
  const size_t dirbase = (size_t)dir * T_LEN * 65536ull;
#pragma unroll
  for (int j = 0; j < 4; j++) {
    int col = n0 + wc * 64 + j * 16 + (l & 15);
    float bb = bias[col];
    size_t coloff = (size_t)((col >> 3) & 63) * 1024 + (size_t)(col >> 9) * 8 + (size_t)(col & 7);
#pragma unroll
    for (int i = 0; i < 4; i++) {
#pragma unroll
      for (int r = 0; r < 4; r++) {
        int row = m0 + wr * 64 + i * 16 + (l >> 4) * 4 + r;
        int t = row >> 5, b = row & 31;
        xpo[dirbase + (size_t)t * 65536 + coloff + (size_t)b * 32] = f2bf(acc[i][j][r] + bb);
      }
    }
  }
}

// ---------------- persistent recurrent scan --------------------------------------------
// 128 WGs: dir = bid>>6, w = bid&63. WG owns hidden units j = w*8 .. w*8+7, all 32 batches.
// Wave (mt,nt): batches mt*16..+15, local outputs nt*16..+15, FULL K=512 (no cross-wave
// K-reduction). h broadcast: per-wave pack in LDS -> 16B sc0sc1 stores -> vmcnt drain ->
// barrier -> one atomic_add to the direction's half-counter. Consumers poll the two
// counters as one u64, then load h via 16x global_load_dwordx4 sc0 sc1 (inline asm).
__global__ __launch_bounds__(256) void lstm_scan(
    const u16* __restrict__ xp, const u16* __restrict__ whhbf,
    const float* __restrict__ c0f, const float* __restrict__ c0b,
    u16* hbuf, u32* flags, float* __restrict__ out)
{
  const int bid = blockIdx.x;
  const int dir = bid >> 6;
  const int w   = bid & 63;
  const int tid = threadIdx.x, l = tid & 63, wv = tid >> 6;
  const int mt = wv >> 1, nt = wv & 1;

  __shared__ u16 Wl[32][520];     // 32 Whh rows (n = g*8+jj), padded
  __shared__ float Gl[32][36];    // gates [batch][g*8+jj]
  __shared__ u16 Htmp[4][64];     // per-wave h pack

  {
    int n = tid >> 3, part = tid & 7;
    int g = n >> 3, jj = n & 7;
    const u16* src = whhbf + ((size_t)dir * G4 + (size_t)g * 512 + w * 8 + jj) * 512 + part * 64;
    u16* dst = &Wl[n][part * 64];
#pragma unroll
    for (int q = 0; q < 8; q++) *(us8*)(dst + q * 8) = *(const us8*)(src + q * 8);
  }
  __syncthreads();

  // weight fragments in registers: full K per wave, 16 frags
  bf16x8 bfr[16];
#pragma unroll
  for (int kk = 0; kk < 16; kk++)
    bfr[kk] = *(const bf16x8*)&Wl[nt * 16 + (l & 15)][kk * 32 + (l >> 4) * 8];

  const int b_ = tid >> 3, jj_ = tid & 7;   // this thread's (batch, local hidden)
  const float* c0 = dir ? c0b : c0f;
  float c = c0[b_ * 512 + w * 8 + jj_];

  u16* hb = hbuf + (size_t)dir * 2 * BATCH * HDIM;
  u32* cnt = flags + dir * 2;               // [cntA (w<32), cntB (w>=32)]
  const int mygrp = w >> 5;
  const u16* xpd = xp + (size_t)dir * T_LEN * 65536ull;
  const int arow = mt * 16 + (l & 15);
  const int ksub = l >> 4;                   // 0..3

  for (int k = 1; k <= T_LEN; k++) {
    const int t = dir ? (T_LEN - k) : (k - 1);

    // xp prefetch: this thread's 4 gate pre-activations (fire early, used post-barrier)
    const u16* xb = xpd + (size_t)t * 65536 + (size_t)w * 1024 + (size_t)b_ * 32 + jj_;
    u16 xr0 = xb[0], xr1 = xb[8], xr2 = xb[16], xr3 = xb[24];

    // poll both half-counters in one u64 load (all lanes same addr -> one request)
    {
      const u32 nv = 32u * (u32)(k - 1);
      for (;;) {
        u64 v = __hip_atomic_load((const u64*)cnt, __ATOMIC_RELAXED, __HIP_MEMORY_SCOPE_AGENT);
        if ((u32)v >= nv && (u32)(v >> 32) >= nv) break;
        __builtin_amdgcn_s_sleep(1);
      }
    }

    // load h_{k-1} fragments: 16 x 16B, agent-coherent, back-to-back
    const u16* hsrc = hb + (size_t)((k - 1) & 1) * (BATCH * HDIM);
    const u16* abase = hsrc + (size_t)arow * 512 + ksub * 8;
    bf16x8 afr[16];
#define LDH(i, offs) \
    asm volatile("global_load_dwordx4 %0, %1, off offset:" offs " sc0 sc1" \
                 : "=v"(afr[i]) : "v"(abase) : "memory");
    LDH(0, "0")   LDH(1, "64")  LDH(2, "128") LDH(3, "192")
    LDH(4, "256") LDH(5, "320") LDH(6, "384") LDH(7, "448")
    LDH(8, "512") LDH(9, "576") LDH(10, "640") LDH(11, "704")
    LDH(12, "768") LDH(13, "832") LDH(14, "896") LDH(15, "960")
#undef LDH
    asm volatile("s_waitcnt vmcnt(0)" ::: "memory");
    __builtin_amdgcn_sched_barrier(0);

    f32x4 accA = (f32x4){0.f, 0.f, 0.f, 0.f};
    f32x4 accB = (f32x4){0.f, 0.f, 0.f, 0.f};
#pragma unroll
    for (int kk = 0; kk < 8; kk++) {
      accA = __builtin_amdgcn_mfma_f32_16x16x32_bf16(afr[kk],     bfr[kk],     accA, 0, 0, 0);
      accB = __builtin_amdgcn_mfma_f32_16x16x32_bf16(afr[kk + 8], bfr[kk + 8], accB, 0, 0, 0);
    }
#pragma unroll
    for (int r = 0; r < 4; r++)
      Gl[mt * 16 + ksub * 4 + r][nt * 16 + (l & 15)] = accA[r] + accB[r];

    __syncthreads();                               // gates ready

    float ai = Gl[b_][jj_]      + bf2f(xr0);
    float af = Gl[b_][8 + jj_]  + bf2f(xr1);
    float ag = Gl[b_][16 + jj_] + bf2f(xr2);
    float ao = Gl[b_][24 + jj_] + bf2f(xr3);
    float si = sigm(ai), sf_ = sigm(af), sg = tanh_(ag), so = sigm(ao);
    c = sf_ * c + si * sg;
    float h = so * tanh_(c);

    // per-wave pack + publish (intra-wave LDS, no extra barrier)
    Htmp[wv][l] = f2bf(h);
    if (l < 8) {
      bf16x8 hv = *(const bf16x8*)&Htmp[wv][l * 8];
      u16* dstp = hb + (size_t)(k & 1) * (BATCH * HDIM) + (size_t)(wv * 8 + l) * 512 + w * 8;
      asm volatile("global_store_dwordx4 %0, %1, off sc0 sc1" :: "v"(dstp), "v"(hv) : "memory");
    }
    asm volatile("s_waitcnt vmcnt(0)" ::: "memory");   // own stores drained to coherence pt
    __syncthreads();                                   // all waves drained
    if (tid == 0)
      __hip_atomic_fetch_add(cnt + mygrp, 1u, __ATOMIC_RELAXED, __HIP_MEMORY_SCOPE_AGENT);

    // output write — registers only, off the critical path, full fp32 h
    out[((size_t)t * 32 + b_) * 1024 + (size_t)dir * 512 + w * 8 + jj_] = h;
  }
}

// ---------------------------------------------------------------------------------------
extern "C" void kernel_launch(void* const* d_in, const int* in_sizes, int n_in,
                              void* d_out, int out_size, void* d_ws, size_t ws_size,
                              hipStream_t stream) {
  if (ws_size < WS_NEED) return;

  const float* x     = (const float*)d_in[0];
  const float* h0_f  = (const float*)d_in[1];
  const float* c0_f  = (const float*)d_in[2];
  const float* h0_b  = (const float*)d_in[3];
  const float* c0_b  = (const float*)d_in[4];
  const float* Wih_f = (const float*)d_in[5];
  const float* Whh_f = (const float*)d_in[6];
  const float* b_f   = (const float*)d_in[7];
  const float* Wih_b = (const float*)d_in[8];
  const float* Whh_b = (const float*)d_in[9];
  const float* b_b   = (const float*)d_in[10];

  char* ws = (char*)d_ws;
  u16* xbf   = (u16*)(ws + XBF_OFF);
  u16* wihbf = (u16*)(ws + WIH_OFF);
  u16* whhbf = (u16*)(ws + WHH_OFF);
  u16* xpw   = (u16*)(ws + XP_OFF);
  u16* hbuf  = (u16*)(ws + HBUF_OFF);
  u32* flags = (u32*)(ws + FLG_OFF);

  prep_kernel<<<4096, 256, 0, stream>>>(
      (const float4*)x, (const float4*)Wih_f, (const float4*)Wih_b,
      (const float4*)Whh_f, (const float4*)Whh_b,
      (const float4*)h0_f, (const float4*)h0_b,
      (ushort4*)xbf, (ushort4*)wihbf, (ushort4*)whhbf, (ushort4*)hbuf, flags);

  dim3 g2(512, 16, 2);
  gemm_xp<<<g2, 256, 0, stream>>>(xbf, wihbf, b_f, b_b, xpw);

  lstm_scan<<<128, 256, 0, stream>>>(xpw, whhbf, c0_f, c0_b, hbuf, flags, (float*)d_out);
}

// Round 4
// 8998.666 us; speedup vs baseline: 1.6743x; 1.6743x over previous
//
#include <hip/hip_runtime.h>
#include <hip/hip_bf16.h>
#include <stdint.h>

typedef unsigned short u16;
typedef unsigned int   u32;
typedef unsigned long long u64;

typedef __attribute__((ext_vector_type(4))) float  f32x4;
typedef __attribute__((ext_vector_type(8))) short  bf16x8;
typedef __attribute__((ext_vector_type(8))) unsigned short us8;

#define T_LEN 2048
#define BATCH 32
#define IDIM  512
#define HDIM  512
#define G4    2048
#define MARK  0x7FC0   // bf16 NaN — impossible output of sigm*tanh

// workspace layout (bytes) — unchanged footprint vs R1 (proven to fit)
#define XBF_OFF   0ull            // bf16 x : 67108864 B (dead after gemm_xp)
#define WIH_OFF   67108864ull     // bf16 wih[2][2048][512] (dead after gemm_xp)
#define HBUF_OFF  67108864ull     // h_hist bf16 [2][4][32][512] = 256 KiB, reuses WIH region
#define WHH_OFF   71303168ull     // bf16 whh[2][2048][512]
#define XP_OFF    75497472ull     // bf16 xp[2][T][w:64][b:32][g:4][u:8]
#define WS_NEED   612499968ull

__device__ __forceinline__ u16 f2bf(float f) {
  u32 u = __float_as_uint(f);
  return (u16)((u + 0x7FFFu + ((u >> 16) & 1u)) >> 16);   // RTNE
}
__device__ __forceinline__ float bf2f(u16 h) {
  return __uint_as_float(((u32)h) << 16);
}
__device__ __forceinline__ float sigm(float x) {
  x = fminf(fmaxf(x, -30.f), 30.f);
  return 1.f / (1.f + __expf(-x));
}
__device__ __forceinline__ float tanh_(float x) {
  x = fminf(fmaxf(x, -15.f), 15.f);
  float e = __expf(2.f * x);
  return (e - 1.f) / (e + 1.f);
}

// ---------------- prep: fp32 -> bf16 conversions (x, weights) ----------------
__global__ __launch_bounds__(256) void prep_kernel(
    const float4* __restrict__ x,
    const float4* __restrict__ wihf, const float4* __restrict__ wihb,
    const float4* __restrict__ whhf, const float4* __restrict__ whhb,
    ushort4* __restrict__ xbf, ushort4* __restrict__ wihbf,
    ushort4* __restrict__ whhbf)
{
  const size_t NX = 8388608, NW = 262144;   // float4 units
  const size_t total = NX + 4 * NW;
  size_t stride = (size_t)gridDim.x * blockDim.x;
  for (size_t i = (size_t)blockIdx.x * blockDim.x + threadIdx.x; i < total; i += stride) {
    const float4* src; ushort4* dst; size_t off;
    if (i < NX)                { src = x;    dst = xbf;          off = i; }
    else if (i < NX + NW)      { src = wihf; dst = wihbf;        off = i - NX; }
    else if (i < NX + 2 * NW)  { src = wihb; dst = wihbf + NW;   off = i - NX - NW; }
    else if (i < NX + 3 * NW)  { src = whhf; dst = whhbf;        off = i - NX - 2 * NW; }
    else                       { src = whhb; dst = whhbf + NW;   off = i - NX - 3 * NW; }
    float4 v = src[off];
    ushort4 o;
    o.x = f2bf(v.x); o.y = f2bf(v.y); o.z = f2bf(v.z); o.w = f2bf(v.w);
    dst[off] = o;
  }
}

// ---------------- prep2 (runs AFTER gemm_xp): seed h_hist into dead WIH region ------------
// layout: hbuf[dir:2][slot:4][32][512] bf16. slot0 = h0, slots 1..3 = MARK.
__global__ __launch_bounds__(256) void prep2_kernel(
    const float4* __restrict__ h0f, const float4* __restrict__ h0b,
    ushort4* __restrict__ hbuf)
{
  size_t i = (size_t)blockIdx.x * blockDim.x + threadIdx.x;   // 32768 ushort4 total
  if (i >= 32768) return;
  const size_t NH = 4096;          // ushort4 per h0 (32*512 u16)
  const size_t DIR = 16384;        // ushort4 per direction (4 slots)
  size_t d = i / DIR, r = i % DIR;
  ushort4 o;
  if (r < NH) {
    float4 v = (d ? h0b : h0f)[r];
    o.x = f2bf(v.x); o.y = f2bf(v.y); o.z = f2bf(v.z); o.w = f2bf(v.w);
  } else {
    o.x = MARK; o.y = MARK; o.z = MARK; o.w = MARK;
  }
  hbuf[i] = o;
}

// ---------------- x-projection GEMM: xp = x @ Wih^T + b (both dirs), permuted store --------
// M=65536 (t*32+b), N=2048, K=512. 128x128 tile, 4 waves, bf16 MFMA. (R1-proven.)
__global__ __launch_bounds__(256, 2) void gemm_xp(
    const u16* __restrict__ xbf, const u16* __restrict__ wihbf,
    const float* __restrict__ bias_f, const float* __restrict__ bias_b,
    u16* __restrict__ xpo)
{
  const int m0 = blockIdx.x * 128;
  const int n0 = blockIdx.y * 128;
  const int dir = blockIdx.z;
  const int tid = threadIdx.x, l = tid & 63, wv = tid >> 6;

  __shared__ u16 As[128 * 72];
  __shared__ u16 Bs[128 * 72];

  const u16* wih = wihbf + (size_t)dir * G4 * IDIM;

  f32x4 acc[4][4];
#pragma unroll
  for (int i = 0; i < 4; i++)
#pragma unroll
    for (int j = 0; j < 4; j++) acc[i][j] = (f32x4){0.f, 0.f, 0.f, 0.f};

  const int srow = tid >> 1, shalf = tid & 1;
  const int wr = wv >> 1, wc = wv & 1;

  for (int k0 = 0; k0 < IDIM; k0 += 64) {
    __syncthreads();
    {
      const u16* ag = xbf + (size_t)(m0 + srow) * IDIM + k0 + shalf * 32;
      const u16* bg = wih + (size_t)(n0 + srow) * IDIM + k0 + shalf * 32;
      u16* ad = &As[srow * 72 + shalf * 32];
      u16* bd = &Bs[srow * 72 + shalf * 32];
#pragma unroll
      for (int q = 0; q < 4; q++) *(us8*)(ad + q * 8) = *(const us8*)(ag + q * 8);
#pragma unroll
      for (int q = 0; q < 4; q++) *(us8*)(bd + q * 8) = *(const us8*)(bg + q * 8);
    }
    __syncthreads();
#pragma unroll
    for (int kk = 0; kk < 2; kk++) {
      bf16x8 af[4], bv[4];
#pragma unroll
      for (int i = 0; i < 4; i++)
        af[i] = *(const bf16x8*)&As[(wr * 64 + i * 16 + (l & 15)) * 72 + kk * 32 + (l >> 4) * 8];
#pragma unroll
      for (int j = 0; j < 4; j++)
        bv[j] = *(const bf16x8*)&Bs[(wc * 64 + j * 16 + (l & 15)) * 72 + kk * 32 + (l >> 4) * 8];
#pragma unroll
      for (int i = 0; i < 4; i++)
#pragma unroll
        for (int j = 0; j < 4; j++)
          acc[i][j] = __builtin_amdgcn_mfma_f32_16x16x32_bf16(af[i], bv[j], acc[i][j], 0, 0, 0);
    }
  }

  const float* bias = dir ? bias_b : bias_f;
  const size_t dirbase = (size_t)dir * T_LEN * 65536ull;
#pragma unroll
  for (int j = 0; j < 4; j++) {
    int col = n0 + wc * 64 + j * 16 + (l & 15);
    float bb = bias[col];
    // per t: [w:64][b:32][g:4][u:8] ; col = g*512 + w*8 + jj
    size_t coloff = (size_t)((col >> 3) & 63) * 1024 + (size_t)(col >> 9) * 8 + (size_t)(col & 7);
#pragma unroll
    for (int i = 0; i < 4; i++) {
#pragma unroll
      for (int r = 0; r < 4; r++) {
        int row = m0 + wr * 64 + i * 16 + (l >> 4) * 4 + r;
        int t = row >> 5, b = row & 31;
        xpo[dirbase + (size_t)t * 65536 + coloff + (size_t)b * 32] = f2bf(acc[i][j][r] + bb);
      }
    }
  }
}

// ---------------- persistent recurrent scan: data-is-the-flag --------------------------
// 128 WGs: dir = bid>>6, w = bid&63. WG owns 8 hidden units x 32 batches.
// 4 waves = (mt: batch-half, kh: K-half), duplication-free h reads.
// h_hist[4] slots; unwritten chunks hold MARK (bf16 NaN). Consumers poll-load their own
// fragments until marker-free (16B chunks are store-atomic -> check 1 u16 per chunk).
// Producers: publish 16B slices sc0 sc1 (no drain, no flag); re-marker slot (k+2)&3.
__global__ __launch_bounds__(256) void lstm_scan(
    const u16* __restrict__ xp, const u16* __restrict__ whhbf,
    const float* __restrict__ c0f, const float* __restrict__ c0b,
    u16* hbuf, float* __restrict__ out)
{
  const int bid = blockIdx.x;
  const int dir = bid >> 6;
  const int w   = bid & 63;
  const int tid = threadIdx.x, l = tid & 63, wv = tid >> 6;
  const int mt = wv >> 1, kh = wv & 1;        // batch-half, K-half
  const int grp = l >> 4;                     // 0..3

  __shared__ u16 Wl[32][520];                 // 32 Whh rows (n = g*8+jj), padded
  __shared__ float Gl[2][32][33];             // per-K-half partial gates
  __shared__ __align__(16) u16 Hp[256];       // h pack [b][jj]

  {
    int n = tid >> 3, part = tid & 7;
    int g = n >> 3, jj = n & 7;
    const u16* src = whhbf + ((size_t)dir * G4 + (size_t)g * 512 + w * 8 + jj) * 512 + part * 64;
    u16* dst = &Wl[n][part * 64];
#pragma unroll
    for (int q = 0; q < 8; q++) *(us8*)(dst + q * 8) = *(const us8*)(src + q * 8);
  }
  __syncthreads();

  // weight fragments in registers: this wave's K-half, two 16-col tiles
  bf16x8 bfr[2][8];
#pragma unroll
  for (int nt = 0; nt < 2; nt++)
#pragma unroll
    for (int kk = 0; kk < 8; kk++)
      bfr[nt][kk] = *(const bf16x8*)&Wl[nt * 16 + (l & 15)][kh * 256 + kk * 32 + grp * 8];

  const int b_ = tid >> 3, jj_ = tid & 7;     // elementwise role (batch, local unit)
  const float* c0 = dir ? c0b : c0f;
  float c = c0[b_ * 512 + w * 8 + jj_];

  u16* hb = hbuf + (size_t)dir * 4 * BATCH * HDIM;   // 4 slots
  const u16* xpd = xp + (size_t)dir * T_LEN * 65536ull;
  const int arow = mt * 16 + (l & 15);

  bf16x8 mkv;
#pragma unroll
  for (int q = 0; q < 8; q++) mkv[q] = (short)MARK;

  for (int k = 1; k <= T_LEN; k++) {
    const int t = dir ? (T_LEN - k) : (k - 1);

    // xp prefetch (plain cached loads; L2-resident stream)
    const u16* xb = xpd + (size_t)t * 65536 + (size_t)w * 1024 + (size_t)b_ * 32 + jj_;
    u16 xr0 = xb[0], xr1 = xb[8], xr2 = xb[16], xr3 = xb[24];

    // poll-load h_{k-1} fragments: 8 x 16B chunks, valid when no chunk is MARK
    const u16* pbase = hb + (size_t)((k - 1) & 3) * (BATCH * HDIM)
                     + (size_t)arow * 512 + kh * 256 + grp * 8;
    bf16x8 afr[8];
    for (;;) {
      asm volatile(
        "global_load_dwordx4 %0, %8, off sc0 sc1\n\t"
        "global_load_dwordx4 %1, %8, off offset:64 sc0 sc1\n\t"
        "global_load_dwordx4 %2, %8, off offset:128 sc0 sc1\n\t"
        "global_load_dwordx4 %3, %8, off offset:192 sc0 sc1\n\t"
        "global_load_dwordx4 %4, %8, off offset:256 sc0 sc1\n\t"
        "global_load_dwordx4 %5, %8, off offset:320 sc0 sc1\n\t"
        "global_load_dwordx4 %6, %8, off offset:384 sc0 sc1\n\t"
        "global_load_dwordx4 %7, %8, off offset:448 sc0 sc1\n\t"
        "s_waitcnt vmcnt(0)"
        : "=&v"(afr[0]), "=&v"(afr[1]), "=&v"(afr[2]), "=&v"(afr[3]),
          "=&v"(afr[4]), "=&v"(afr[5]), "=&v"(afr[6]), "=&v"(afr[7])
        : "v"(pbase) : "memory");
      int bad = 0;
#pragma unroll
      for (int q = 0; q < 8; q++) bad |= (afr[q][0] == (short)MARK);
      if (!__any(bad)) break;
      __builtin_amdgcn_s_sleep(1);
    }
    __builtin_amdgcn_sched_barrier(0);

    f32x4 accA = (f32x4){0.f, 0.f, 0.f, 0.f};
    f32x4 accB = (f32x4){0.f, 0.f, 0.f, 0.f};
#pragma unroll
    for (int kk = 0; kk < 8; kk++) {
      accA = __builtin_amdgcn_mfma_f32_16x16x32_bf16(afr[kk], bfr[0][kk], accA, 0, 0, 0);
      accB = __builtin_amdgcn_mfma_f32_16x16x32_bf16(afr[kk], bfr[1][kk], accB, 0, 0, 0);
    }
#pragma unroll
    for (int r = 0; r < 4; r++) {
      Gl[kh][mt * 16 + grp * 4 + r][(l & 15)]      = accA[r];
      Gl[kh][mt * 16 + grp * 4 + r][16 + (l & 15)] = accB[r];
    }
    __syncthreads();                               // gates ready

    float ai = Gl[0][b_][jj_]      + Gl[1][b_][jj_]      + bf2f(xr0);
    float af = Gl[0][b_][8 + jj_]  + Gl[1][b_][8 + jj_]  + bf2f(xr1);
    float ag = Gl[0][b_][16 + jj_] + Gl[1][b_][16 + jj_] + bf2f(xr2);
    float ao = Gl[0][b_][24 + jj_] + Gl[1][b_][24 + jj_] + bf2f(xr3);
    float si = sigm(ai), sf_ = sigm(af), sg = tanh_(ag), so = sigm(ao);
    c = sf_ * c + si * sg;
    float h = so * tanh_(c);
    Hp[b_ * 8 + jj_] = f2bf(h);
    __syncthreads();                               // Hp packed; also orders next-iter Gl reuse

    if (wv == 0 && l < 32) {                       // publish h_k slice: 32 x 16B, no drain
      bf16x8 hv = *(const bf16x8*)&Hp[l * 8];
      u16* dstp = hb + (size_t)(k & 3) * (BATCH * HDIM) + (size_t)l * 512 + w * 8;
      asm volatile("global_store_dwordx4 %0, %1, off sc0 sc1" :: "v"(dstp), "v"(hv) : "memory");
    }
    if (wv == 1 && l < 32) {                       // re-marker slot (k+2)&3 (own slice)
      u16* cdst = hb + (size_t)((k + 2) & 3) * (BATCH * HDIM) + (size_t)l * 512 + w * 8;
      asm volatile("global_store_dwordx4 %0, %1, off sc0 sc1" :: "v"(cdst), "v"(mkv) : "memory");
    }

    // output from registers — off the critical path, plain fp32 store
    out[((size_t)t * 32 + b_) * 1024 + (size_t)dir * 512 + w * 8 + jj_] = h;
  }
}

// ---------------------------------------------------------------------------------------
extern "C" void kernel_launch(void* const* d_in, const int* in_sizes, int n_in,
                              void* d_out, int out_size, void* d_ws, size_t ws_size,
                              hipStream_t stream) {
  if (ws_size < WS_NEED) return;

  const float* x     = (const float*)d_in[0];
  const float* h0_f  = (const float*)d_in[1];
  const float* c0_f  = (const float*)d_in[2];
  const float* h0_b  = (const float*)d_in[3];
  const float* c0_b  = (const float*)d_in[4];
  const float* Wih_f = (const float*)d_in[5];
  const float* Whh_f = (const float*)d_in[6];
  const float* b_f   = (const float*)d_in[7];
  const float* Wih_b = (const float*)d_in[8];
  const float* Whh_b = (const float*)d_in[9];
  const float* b_b   = (const float*)d_in[10];

  char* ws = (char*)d_ws;
  u16* xbf   = (u16*)(ws + XBF_OFF);
  u16* wihbf = (u16*)(ws + WIH_OFF);
  u16* whhbf = (u16*)(ws + WHH_OFF);
  u16* xpw   = (u16*)(ws + XP_OFF);
  u16* hbuf  = (u16*)(ws + HBUF_OFF);   // overlays WIH region (dead after gemm_xp)

  prep_kernel<<<4096, 256, 0, stream>>>(
      (const float4*)x, (const float4*)Wih_f, (const float4*)Wih_b,
      (const float4*)Whh_f, (const float4*)Whh_b,
      (ushort4*)xbf, (ushort4*)wihbf, (ushort4*)whhbf);

  dim3 g2(512, 16, 2);
  gemm_xp<<<g2, 256, 0, stream>>>(xbf, wihbf, b_f, b_b, xpw);

  prep2_kernel<<<128, 256, 0, stream>>>(
      (const float4*)h0_f, (const float4*)h0_b, (ushort4*)hbuf);

  lstm_scan<<<128, 256, 0, stream>>>(xpw, whhbf, c0_f, c0_b, hbuf, (float*)d_out);
}

// Round 6
// 7475.713 us; speedup vs baseline: 2.0154x; 1.2037x over previous
//
#include <hip/hip_runtime.h>
#include <hip/hip_bf16.h>
#include <stdint.h>

typedef unsigned short u16;
typedef unsigned int   u32;
typedef unsigned long long u64;

typedef __attribute__((ext_vector_type(4))) float  f32x4;
typedef __attribute__((ext_vector_type(8))) short  bf16x8;
typedef __attribute__((ext_vector_type(8))) unsigned short us8;

#define T_LEN 2048
#define BATCH 32
#define IDIM  512
#define HDIM  512
#define G4    2048
#define MARK  0x7FC0   // bf16 NaN — impossible output of sigm*tanh (both clamped finite)

// workspace layout (bytes)
#define XBF_OFF   0ull            // bf16 x : 67108864 B (dead after gemm_xp)
#define WIH_OFF   67108864ull     // bf16 wih[2][2048][512] (dead after gemm_xp)
#define HBUF_OFF  67108864ull     // h_hist bf16 [2][4][32][512] = 256 KiB, reuses WIH region
#define WHH_OFF   71303168ull     // bf16 whh[2][2048][512]
#define XP_OFF    75497472ull     // bf16 xp[2][T][w:32][b:32][g:4][u:16]
#define WS_NEED   612499968ull

__device__ __forceinline__ u16 f2bf(float f) {
  u32 u = __float_as_uint(f);
  return (u16)((u + 0x7FFFu + ((u >> 16) & 1u)) >> 16);   // RTNE
}
__device__ __forceinline__ float bf2f(u16 h) {
  return __uint_as_float(((u32)h) << 16);
}
__device__ __forceinline__ float sigm(float x) {
  x = fminf(fmaxf(x, -30.f), 30.f);
  return 1.f / (1.f + __expf(-x));
}
__device__ __forceinline__ float tanh_(float x) {
  x = fminf(fmaxf(x, -15.f), 15.f);
  float e = __expf(2.f * x);
  return (e - 1.f) / (e + 1.f);
}

// ---------------- prep: fp32 -> bf16 conversions (x, weights) ----------------
__global__ __launch_bounds__(256) void prep_kernel(
    const float4* __restrict__ x,
    const float4* __restrict__ wihf, const float4* __restrict__ wihb,
    const float4* __restrict__ whhf, const float4* __restrict__ whhb,
    ushort4* __restrict__ xbf, ushort4* __restrict__ wihbf,
    ushort4* __restrict__ whhbf)
{
  const size_t NX = 8388608, NW = 262144;   // float4 units
  const size_t total = NX + 4 * NW;
  size_t stride = (size_t)gridDim.x * blockDim.x;
  for (size_t i = (size_t)blockIdx.x * blockDim.x + threadIdx.x; i < total; i += stride) {
    const float4* src; ushort4* dst; size_t off;
    if (i < NX)                { src = x;    dst = xbf;          off = i; }
    else if (i < NX + NW)      { src = wihf; dst = wihbf;        off = i - NX; }
    else if (i < NX + 2 * NW)  { src = wihb; dst = wihbf + NW;   off = i - NX - NW; }
    else if (i < NX + 3 * NW)  { src = whhf; dst = whhbf;        off = i - NX - 2 * NW; }
    else                       { src = whhb; dst = whhbf + NW;   off = i - NX - 3 * NW; }
    float4 v = src[off];
    ushort4 o;
    o.x = f2bf(v.x); o.y = f2bf(v.y); o.z = f2bf(v.z); o.w = f2bf(v.w);
    dst[off] = o;
  }
}

// ---------------- prep2 (runs AFTER gemm_xp): seed h_hist into dead WIH region ------------
// layout: hbuf[dir:2][slot:4][32][512] bf16. slot0 = h0, slots 1..3 = MARK.
__global__ __launch_bounds__(256) void prep2_kernel(
    const float4* __restrict__ h0f, const float4* __restrict__ h0b,
    ushort4* __restrict__ hbuf)
{
  size_t i = (size_t)blockIdx.x * blockDim.x + threadIdx.x;   // 32768 ushort4 total
  if (i >= 32768) return;
  const size_t NH = 4096;          // ushort4 per h0 (32*512 u16)
  const size_t DIR = 16384;        // ushort4 per direction (4 slots)
  size_t d = i / DIR, r = i % DIR;
  ushort4 o;
  if (r < NH) {
    float4 v = (d ? h0b : h0f)[r];
    o.x = f2bf(v.x); o.y = f2bf(v.y); o.z = f2bf(v.z); o.w = f2bf(v.w);
  } else {
    o.x = MARK; o.y = MARK; o.z = MARK; o.w = MARK;
  }
  hbuf[i] = o;
}

// ---------------- x-projection GEMM: xp = x @ Wih^T + b (both dirs), permuted store --------
// M=65536 (t*32+b), N=2048, K=512. 128x128 tile, 4 waves, bf16 MFMA. (R1-proven.)
// Store layout per t: [w:32][b:32][g:4][u:16];  col = g*512 + w*16 + u.
__global__ __launch_bounds__(256, 2) void gemm_xp(
    const u16* __restrict__ xbf, const u16* __restrict__ wihbf,
    const float* __restrict__ bias_f, const float* __restrict__ bias_b,
    u16* __restrict__ xpo)
{
  const int m0 = blockIdx.x * 128;
  const int n0 = blockIdx.y * 128;
  const int dir = blockIdx.z;
  const int tid = threadIdx.x, l = tid & 63, wv = tid >> 6;

  __shared__ u16 As[128 * 72];
  __shared__ u16 Bs[128 * 72];

  const u16* wih = wihbf + (size_t)dir * G4 * IDIM;

  f32x4 acc[4][4];
#pragma unroll
  for (int i = 0; i < 4; i++)
#pragma unroll
    for (int j = 0; j < 4; j++) acc[i][j] = (f32x4){0.f, 0.f, 0.f, 0.f};

  const int srow = tid >> 1, shalf = tid & 1;
  const int wr = wv >> 1, wc = wv & 1;

  for (int k0 = 0; k0 < IDIM; k0 += 64) {
    __syncthreads();
    {
      const u16* ag = xbf + (size_t)(m0 + srow) * IDIM + k0 + shalf * 32;
      const u16* bg = wih + (size_t)(n0 + srow) * IDIM + k0 + shalf * 32;
      u16* ad = &As[srow * 72 + shalf * 32];
      u16* bd = &Bs[srow * 72 + shalf * 32];
#pragma unroll
      for (int q = 0; q < 4; q++) *(us8*)(ad + q * 8) = *(const us8*)(ag + q * 8);
#pragma unroll
      for (int q = 0; q < 4; q++) *(us8*)(bd + q * 8) = *(const us8*)(bg + q * 8);
    }
    __syncthreads();
#pragma unroll
    for (int kk = 0; kk < 2; kk++) {
      bf16x8 af[4], bv[4];
#pragma unroll
      for (int i = 0; i < 4; i++)
        af[i] = *(const bf16x8*)&As[(wr * 64 + i * 16 + (l & 15)) * 72 + kk * 32 + (l >> 4) * 8];
#pragma unroll
      for (int j = 0; j < 4; j++)
        bv[j] = *(const bf16x8*)&Bs[(wc * 64 + j * 16 + (l & 15)) * 72 + kk * 32 + (l >> 4) * 8];
#pragma unroll
      for (int i = 0; i < 4; i++)
#pragma unroll
        for (int j = 0; j < 4; j++)
          acc[i][j] = __builtin_amdgcn_mfma_f32_16x16x32_bf16(af[i], bv[j], acc[i][j], 0, 0, 0);
    }
  }

  const float* bias = dir ? bias_b : bias_f;
  const size_t dirbase = (size_t)dir * T_LEN * 65536ull;
#pragma unroll
  for (int j = 0; j < 4; j++) {
    int col = n0 + wc * 64 + j * 16 + (l & 15);
    float bb = bias[col];
    // col = g*512 + w*16 + u  ->  [w:32][b:32][g:4][u:16]
    size_t coloff = (size_t)((col >> 4) & 31) * 2048 + (size_t)(col >> 9) * 16 + (size_t)(col & 15);
#pragma unroll
    for (int i = 0; i < 4; i++) {
#pragma unroll
      for (int r = 0; r < 4; r++) {
        int row = m0 + wr * 64 + i * 16 + (l >> 4) * 4 + r;
        int t = row >> 5, b = row & 31;
        xpo[dirbase + (size_t)t * 65536 + coloff + (size_t)b * 64] = f2bf(acc[i][j][r] + bb);
      }
    }
  }
}

// ---------------- persistent recurrent scan: data-is-the-flag (R4 protocol) --------------
// 64 WGs: dir = bid>>5, w = bid&31. WG owns 16 hidden units x 32 batches.
// Whh slice (64 gate-rows x 512) lives entirely in registers (128 VGPR/lane).
// 4 waves = (mt: batch-half, kh: K-half). Wave (mt,kh): gates[16 batches, 64 cols] partial
// over its 256-wide K-half; cross-wave K-reduction through LDS.
// Poll: 8x16B chunk loads sc0 sc1; retry only lanes still holding a MARK chunk.
// Publish/clear: fire-and-forget sc0 sc1; slot (k+2)&3 re-markered (ordering proof = R4).
__global__ __launch_bounds__(256, 1) void lstm_scan(
    const u16* __restrict__ xp, const u16* __restrict__ whhbf,
    const float* __restrict__ c0f, const float* __restrict__ c0b,
    u16* hbuf, float* __restrict__ out)
{
  const int bid = blockIdx.x;
  const int dir = bid >> 5;
  const int w   = bid & 31;
  const int tid = threadIdx.x, l = tid & 63, wv = tid >> 6;
  const int mt = wv >> 1, kh = wv & 1;        // batch-half, K-half
  const int grp = l >> 4, lr = l & 15;

  __shared__ float Gl[2][32][68];             // [kh][batch][g*16+u], padded
  __shared__ __align__(16) u16 Hp[512];       // [b][u:16]

  // Whh fragments straight to registers: gate g, K-subtile kk (this wave's K-half)
  bf16x8 bfr[4][8];
#pragma unroll
  for (int g = 0; g < 4; g++) {
    const u16* wrow = whhbf + ((size_t)dir * G4 + (size_t)g * 512 + w * 16 + lr) * 512
                    + kh * 256 + grp * 8;
#pragma unroll
    for (int kk = 0; kk < 8; kk++)
      bfr[g][kk] = *(const bf16x8*)(wrow + kk * 32);
  }

  const int b_ = tid >> 3, u0 = tid & 7;      // elementwise: batch b_, units u0 and u0+8
  const float* c0 = dir ? c0b : c0f;
  float cA = c0[b_ * 512 + w * 16 + u0];
  float cB = c0[b_ * 512 + w * 16 + u0 + 8];

  u16* hb = hbuf + (size_t)dir * 4 * BATCH * HDIM;   // 4 slots
  const u16* xpd = xp + (size_t)dir * T_LEN * 65536ull;
  const int arow = mt * 16 + lr;

  bf16x8 mkv;
#pragma unroll
  for (int q = 0; q < 8; q++) mkv[q] = (short)MARK;

#define LOAD8                                                              \
    asm volatile(                                                          \
      "global_load_dwordx4 %0, %8, off sc0 sc1\n\t"                        \
      "global_load_dwordx4 %1, %8, off offset:64 sc0 sc1\n\t"              \
      "global_load_dwordx4 %2, %8, off offset:128 sc0 sc1\n\t"             \
      "global_load_dwordx4 %3, %8, off offset:192 sc0 sc1\n\t"             \
      "global_load_dwordx4 %4, %8, off offset:256 sc0 sc1\n\t"             \
      "global_load_dwordx4 %5, %8, off offset:320 sc0 sc1\n\t"             \
      "global_load_dwordx4 %6, %8, off offset:384 sc0 sc1\n\t"             \
      "global_load_dwordx4 %7, %8, off offset:448 sc0 sc1\n\t"             \
      "s_waitcnt vmcnt(0)"                                                 \
      : "=&v"(afr[0]), "=&v"(afr[1]), "=&v"(afr[2]), "=&v"(afr[3]),        \
        "=&v"(afr[4]), "=&v"(afr[5]), "=&v"(afr[6]), "=&v"(afr[7])         \
      : "v"(pbase) : "memory")

  for (int k = 1; k <= T_LEN; k++) {
    const int t = dir ? (T_LEN - k) : (k - 1);

    // xp prefetch: 8 gate pre-activations (units u0, u0+8), plain cached loads
    const u16* xb = xpd + (size_t)t * 65536 + (size_t)w * 2048 + (size_t)b_ * 64 + u0;
    u16 xi0 = xb[0],  xiB = xb[8];
    u16 xf0 = xb[16], xfB = xb[24];
    u16 xg0 = xb[32], xgB = xb[40];
    u16 xo0 = xb[48], xoB = xb[56];

    // poll-load h_{k-1}: 8 x 16B chunks; straggler-masked retries
    const u16* pbase = hb + (size_t)((k - 1) & 3) * (BATCH * HDIM)
                     + (size_t)arow * 512 + kh * 256 + grp * 8;
    bf16x8 afr[8];
    LOAD8;
    for (;;) {
      int bad = 0;
#pragma unroll
      for (int q = 0; q < 8; q++) bad |= (afr[q][0] == (short)MARK);
      if (!__any(bad)) break;
      __builtin_amdgcn_s_sleep(2);
      if (bad) { LOAD8; }
    }
    __builtin_amdgcn_sched_barrier(0);

    f32x4 acc[4];
#pragma unroll
    for (int g = 0; g < 4; g++) acc[g] = (f32x4){0.f, 0.f, 0.f, 0.f};
#pragma unroll
    for (int kk = 0; kk < 8; kk++) {
#pragma unroll
      for (int g = 0; g < 4; g++)
        acc[g] = __builtin_amdgcn_mfma_f32_16x16x32_bf16(afr[kk], bfr[g][kk], acc[g], 0, 0, 0);
    }
#pragma unroll
    for (int g = 0; g < 4; g++)
#pragma unroll
      for (int r = 0; r < 4; r++)
        Gl[kh][mt * 16 + grp * 4 + r][g * 16 + lr] = acc[g][r];
    __syncthreads();                               // gates ready

    // elementwise: two units per thread
    float ai = Gl[0][b_][u0]      + Gl[1][b_][u0]      + bf2f(xi0);
    float af = Gl[0][b_][16 + u0] + Gl[1][b_][16 + u0] + bf2f(xf0);
    float ag = Gl[0][b_][32 + u0] + Gl[1][b_][32 + u0] + bf2f(xg0);
    float ao = Gl[0][b_][48 + u0] + Gl[1][b_][48 + u0] + bf2f(xo0);
    float si = sigm(ai), sf_ = sigm(af), sg = tanh_(ag), so = sigm(ao);
    cA = sf_ * cA + si * sg;
    float hA = so * tanh_(cA);

    const int u1 = u0 + 8;
    ai = Gl[0][b_][u1]      + Gl[1][b_][u1]      + bf2f(xiB);
    af = Gl[0][b_][16 + u1] + Gl[1][b_][16 + u1] + bf2f(xfB);
    ag = Gl[0][b_][32 + u1] + Gl[1][b_][32 + u1] + bf2f(xgB);
    ao = Gl[0][b_][48 + u1] + Gl[1][b_][48 + u1] + bf2f(xoB);
    si = sigm(ai); sf_ = sigm(af); sg = tanh_(ag); so = sigm(ao);
    cB = sf_ * cB + si * sg;
    float hB = so * tanh_(cB);

    Hp[b_ * 16 + u0] = f2bf(hA);
    Hp[b_ * 16 + u1] = f2bf(hB);
    __syncthreads();                               // Hp packed

    if (wv == 0) {                                 // publish h_k: 64 x 16B, fire-and-forget
      bf16x8 hv = *(const bf16x8*)&Hp[l * 8];
      u16* dstp = hb + (size_t)(k & 3) * (BATCH * HDIM) + (size_t)(l >> 1) * 512
                + w * 16 + (l & 1) * 8;
      asm volatile("global_store_dwordx4 %0, %1, off sc0 sc1" :: "v"(dstp), "v"(hv) : "memory");
    }
    if (wv == 1) {                                 // re-marker slot (k+2)&3 (own slice)
      u16* cdst = hb + (size_t)((k + 2) & 3) * (BATCH * HDIM) + (size_t)(l >> 1) * 512
                + w * 16 + (l & 1) * 8;
      asm volatile("global_store_dwordx4 %0, %1, off sc0 sc1" :: "v"(cdst), "v"(mkv) : "memory");
    }

    // output from registers — off the critical path
    size_t obase = ((size_t)t * 32 + b_) * 1024 + (size_t)dir * 512 + w * 16;
    out[obase + u0] = hA;
    out[obase + u1] = hB;
  }
#undef LOAD8
}

// ---------------------------------------------------------------------------------------
extern "C" void kernel_launch(void* const* d_in, const int* in_sizes, int n_in,
                              void* d_out, int out_size, void* d_ws, size_t ws_size,
                              hipStream_t stream) {
  if (ws_size < WS_NEED) return;

  const float* x     = (const float*)d_in[0];
  const float* h0_f  = (const float*)d_in[1];
  const float* c0_f  = (const float*)d_in[2];
  const float* h0_b  = (const float*)d_in[3];
  const float* c0_b  = (const float*)d_in[4];
  const float* Wih_f = (const float*)d_in[5];
  const float* Whh_f = (const float*)d_in[6];
  const float* b_f   = (const float*)d_in[7];
  const float* Wih_b = (const float*)d_in[8];
  const float* Whh_b = (const float*)d_in[9];
  const float* b_b   = (const float*)d_in[10];

  char* ws = (char*)d_ws;
  u16* xbf   = (u16*)(ws + XBF_OFF);
  u16* wihbf = (u16*)(ws + WIH_OFF);
  u16* whhbf = (u16*)(ws + WHH_OFF);
  u16* xpw   = (u16*)(ws + XP_OFF);
  u16* hbuf  = (u16*)(ws + HBUF_OFF);   // overlays WIH region (dead after gemm_xp)

  prep_kernel<<<4096, 256, 0, stream>>>(
      (const float4*)x, (const float4*)Wih_f, (const float4*)Wih_b,
      (const float4*)Whh_f, (const float4*)Whh_b,
      (ushort4*)xbf, (ushort4*)wihbf, (ushort4*)whhbf);

  dim3 g2(512, 16, 2);
  gemm_xp<<<g2, 256, 0, stream>>>(xbf, wihbf, b_f, b_b, xpw);

  prep2_kernel<<<128, 256, 0, stream>>>(
      (const float4*)h0_f, (const float4*)h0_b, (ushort4*)hbuf);

  lstm_scan<<<64, 256, 0, stream>>>(xpw, whhbf, c0_f, c0_b, hbuf, (float*)d_out);
}